// Round 16
// baseline (275.553 us; speedup 1.0000x reference)
//
#include <hip/hip_runtime.h>
#include <cstddef>

// Shapes: B=64, C=128, Ch=64, H=W=56, N=3136, G=2, K=3, heads=2, hd=32, Nk=196, inner=16
#define NPIX 3136

typedef __attribute__((ext_vector_type(8))) short bf16x8;
typedef __attribute__((ext_vector_type(4))) float f32x4;

__device__ __forceinline__ float gelu_f(float x){
  return 0.5f*x*(1.0f+erff(x*0.70710678118654752440f));
}

__device__ __forceinline__ unsigned pack_bf16(float a, float b){
  unsigned ua = __float_as_uint(a), ub = __float_as_uint(b);
  ua = (ua + 0x7FFFu + ((ua>>16)&1u)) >> 16;
  ub = (ub + 0x7FFFu + ((ub>>16)&1u)) >> 16;
  return ua | (ub<<16);
}

__device__ __forceinline__ unsigned cvt_pk_bf16(float a, float b){
  unsigned r;
  asm("v_cvt_pk_bf16_f32 %0, %1, %2" : "=v"(r) : "v"(a), "v"(b));
  return r;
}

__device__ __forceinline__ float bf16lo(unsigned u){ return __uint_as_float(u<<16); }
__device__ __forceinline__ float bf16hi(unsigned u){ return __uint_as_float(u & 0xFFFF0000u); }

// ---------------- K1: adaptive_avg_pool(3x3, overlapping) + full mean, float4 loads ----------
__global__ void k_pool(const float* __restrict__ x, float* __restrict__ pooled, float* __restrict__ xmean){
  int b = blockIdx.x >> 6, c = blockIdx.x & 63;
  const float4* xp = (const float4*)(x + ((size_t)(b*128 + c))*NPIX);
  float r[9] = {0,0,0,0,0,0,0,0,0};
  float tot = 0.f;
  for (int p4 = threadIdx.x; p4 < 784; p4 += 64){
    float4 v4 = xp[p4];
    int p = p4*4;
    int h = p/56, w0 = p%56;
    bool h0 = (h<=18), h1 = (h>=18 && h<=37), h2 = (h>=37);
    float vv[4] = {v4.x, v4.y, v4.z, v4.w};
    #pragma unroll
    for (int j=0;j<4;j++){
      int w = w0+j; float v = vv[j];
      tot += v;
      bool b0 = (w<=18), b1 = (w>=18 && w<=37), b2 = (w>=37);
      if(h0){ if(b0) r[0]+=v; if(b1) r[1]+=v; if(b2) r[2]+=v; }
      if(h1){ if(b0) r[3]+=v; if(b1) r[4]+=v; if(b2) r[5]+=v; }
      if(h2){ if(b0) r[6]+=v; if(b1) r[7]+=v; if(b2) r[8]+=v; }
    }
  }
  #pragma unroll
  for (int o=32;o>0;o>>=1){
    #pragma unroll
    for (int k=0;k<9;k++) r[k]+=__shfl_xor(r[k],o);
    tot += __shfl_xor(tot,o);
  }
  if (threadIdx.x==0){
    const float cs[3]={19.f,20.f,19.f};
    #pragma unroll
    for(int i=0;i<3;i++)
      #pragma unroll
      for(int j=0;j<3;j++)
        pooled[(size_t)blockIdx.x*9 + i*3+j] = r[i*3+j]/(cs[i]*cs[j]);
    xmean[blockIdx.x] = tot*(1.f/3136.f);
  }
}

// ---------------- K2: dc_proj + softmax over G; build weight + dyn_bias ----
__global__ void k_dcproj(const float* __restrict__ pooled, const float* __restrict__ xmean,
    const float* __restrict__ dcp1_w, const float* __restrict__ dcp1_g, const float* __restrict__ dcp1_b,
    const float* __restrict__ dcp2_w, const float* __restrict__ dcp2_b,
    const float* __restrict__ dc_w, const float* __restrict__ dc_b,
    float* __restrict__ weightO, float* __restrict__ dyn_bias){
  int b = blockIdx.x; int tid = threadIdx.x;
  __shared__ float sp[576], sm[64], t1[144], t1b[16], s2[1152], s2b[128];
  for (int i=tid;i<576;i+=256) sp[i]=pooled[(size_t)b*576+i];
  if (tid<64) sm[tid]=xmean[b*64+tid];
  __syncthreads();
  for (int idx=tid; idx<160; idx+=256){
    if (idx<144){
      int o=idx/9, pos=idx%9; float s=0.f;
      for(int c2=0;c2<64;c2++) s += sp[c2*9+pos]*dcp1_w[o*64+c2];
      t1[idx]=gelu_f(s*dcp1_g[o]+dcp1_b[o]);
    } else {
      int o=idx-144; float s=0.f;
      for(int c2=0;c2<64;c2++) s+=sm[c2]*dcp1_w[o*64+c2];
      t1b[o]=gelu_f(s*dcp1_g[o]+dcp1_b[o]);
    }
  }
  __syncthreads();
  for (int idx=tid; idx<1280; idx+=256){
    if (idx<1152){
      int o=idx/9,pos=idx%9; float s=dcp2_b[o];
      #pragma unroll
      for(int i=0;i<16;i++) s+=t1[i*9+pos]*dcp2_w[o*16+i];
      s2[idx]=s;
    } else {
      int o=idx-1152; float s=dcp2_b[o];
      #pragma unroll
      for(int i=0;i<16;i++) s+=t1b[i]*dcp2_w[o*16+i];
      s2b[o]=s;
    }
  }
  __syncthreads();
  for (int idx=tid; idx<640; idx+=256){
    if (idx<576){
      int ch=idx/9, pos=idx%9;
      float a=s2[ch*9+pos], bb=s2[(64+ch)*9+pos];
      float m=fmaxf(a,bb); float e0=expf(a-m), e1=expf(bb-m); float w0=e0/(e0+e1);
      weightO[(size_t)b*576+idx] = w0*dc_w[ch*9+pos] + (1.f-w0)*dc_w[576+ch*9+pos];
    } else {
      int ch=idx-576;
      float a=s2b[ch], bb=s2b[64+ch];
      float m=fmaxf(a,bb); float e0=expf(a-m), e1=expf(bb-m); float w0=e0/(e0+e1);
      dyn_bias[b*64+ch] = w0*dc_b[ch] + (1.f-w0)*dc_b[64+ch];
    }
  }
}

// ---------------- K3: dynamic dw 3x3 on x1, 2 ch/block -> packed bf16 pair dwords ybf -------
__global__ void k_y1(const float* __restrict__ x, const float* __restrict__ weightO,
                     const float* __restrict__ dyn_bias, unsigned* __restrict__ ybf){
  __shared__ float XS[2*NPIX];
  int b = blockIdx.x>>5, cp = blockIdx.x&31;
  int c0 = 2*cp;
  int tid = threadIdx.x;
  const float4* xp0 = (const float4*)(x + ((size_t)(b*128+c0))*NPIX);
  const float4* xp1 = (const float4*)(x + ((size_t)(b*128+c0+1))*NPIX);
  float4* XS4 = (float4*)XS;
  for (int i=tid;i<784;i+=256){ XS4[i]=xp0[i]; XS4[784+i]=xp1[i]; }
  float w9a[9], w9b[9];
  #pragma unroll
  for (int k=0;k<9;k++){ w9a[k]=weightO[((size_t)(b*64+c0))*9+k]; w9b[k]=weightO[((size_t)(b*64+c0+1))*9+k]; }
  float biasA = dyn_bias[b*64+c0], biasB = dyn_bias[b*64+c0+1];
  __syncthreads();
  unsigned* yp = ybf + ((size_t)(b*64+cp))*NPIX;
  for (int p4=tid;p4<784;p4+=256){
    int h=p4/14, w0=(p4%14)*4;
    unsigned pk[4];
    #pragma unroll
    for (int j=0;j<4;j++){
      int w=w0+j; float aA=biasA, aB=biasB;
      #pragma unroll
      for (int i=0;i<3;i++){ int hh=h+i-1; if((unsigned)hh<56u){
        #pragma unroll
        for(int jj=0;jj<3;jj++){ int ww=w+jj-1; if((unsigned)ww<56u){
          aA += XS[hh*56+ww]*w9a[i*3+jj];
          aB += XS[NPIX+hh*56+ww]*w9b[i*3+jj]; } } } }
      pk[j] = pack_bf16(aA, aB);
    }
    uint4 res = {pk[0],pk[1],pk[2],pk[3]};
    *(uint4*)(yp + h*56 + w0) = res;
  }
}

// ---------------- K4: q projection -> packed bf16 rows, PRE-SCALED by 1/sqrt(32) ------------
__global__ void k_qproj(const float* __restrict__ x, const float* __restrict__ q_w,
                        const float* __restrict__ q_b, unsigned* __restrict__ qbf){
  int b = blockIdx.x/49, t = blockIdx.x%49; int n0 = t*64; int tid = threadIdx.x;
  __shared__ float qwT[64*64]; // [c][o]
  __shared__ float xt[64*64];  // [c][p]
  for (int i4=tid; i4<1024; i4+=256){ int o=i4>>4, c4=(i4&15)*4;
    float4 w4 = *(const float4*)(q_w + o*64 + c4);
    qwT[(c4+0)*64+o]=w4.x; qwT[(c4+1)*64+o]=w4.y; qwT[(c4+2)*64+o]=w4.z; qwT[(c4+3)*64+o]=w4.w; }
  for (int i4=tid; i4<1024; i4+=256){ int c2=i4>>4, p4=(i4&15)*4;
    float4 v4 = *(const float4*)(x + ((size_t)(b*128+64+c2))*NPIX + n0 + p4);
    *(float4*)(xt + c2*64 + p4) = v4; }
  __syncthreads();
  int d2_ = tid&31, prow = tid>>5;
  int o0 = 2*d2_; int h = d2_>>4, dd = d2_&15;
  float b0 = q_b[o0], b1 = q_b[o0+1];
  float a0[8], a1[8];
  #pragma unroll
  for (int i=0;i<8;i++){ a0[i]=b0; a1[i]=b1; }
  #pragma unroll 4
  for (int c2=0;c2<64;c2++){
    float w0 = qwT[c2*64+o0], w1 = qwT[c2*64+o0+1];
    #pragma unroll
    for (int i=0;i<8;i++){ float xv = xt[c2*64 + prow*8 + i]; a0[i]+=xv*w0; a1[i]+=xv*w1; }
  }
  const float sc = 0.17677669529663687f; // 1/sqrt(32), folded into Q
  #pragma unroll
  for (int i=0;i<8;i++)
    qbf[((size_t)(b*2+h)*NPIX + n0 + prow*8 + i)*16 + dd] = pack_bf16(a0[i]*sc, a1[i]*sc);
}

// ---------------- K5a: 7x7 s4 p3 depthwise + BN/GELU + sr2 BN -> kv2, float4 staging --------
__global__ void k_sr(const float* __restrict__ x, const float* __restrict__ sr1_w,
                     const float* __restrict__ sr1_g, const float* __restrict__ sr1_b,
                     const float* __restrict__ sr2_w, const float* __restrict__ sr2_g,
                     const float* __restrict__ sr2_b, float* __restrict__ kv2){
  int b=blockIdx.x>>6, c=blockIdx.x&63;
  __shared__ float pl[NPIX];
  const float4* xp4 = (const float4*)(x + ((size_t)(b*128+64+c))*NPIX);
  float4* pl4 = (float4*)pl;
  for (int i=threadIdx.x;i<784;i+=256) pl4[i]=xp4[i];
  __syncthreads();
  int t=threadIdx.x;
  if (t<196){
    int oy=t/14, ox=t%14;
    float acc=0.f;
    #pragma unroll
    for(int i=0;i<7;i++){ int yy=oy*4-3+i; if((unsigned)yy<56u){
      #pragma unroll
      for(int j=0;j<7;j++){ int xx=ox*4-3+j; if((unsigned)xx<56u) acc += pl[yy*56+xx]*sr1_w[c*49+i*7+j]; } } }
    float g = gelu_f(acc*sr1_g[c]+sr1_b[c]);
    kv2[(size_t)blockIdx.x*196+t] = (g*sr2_w[c])*sr2_g[c]+sr2_b[c];
  }
}

// ---------------- K5b: 3x3 depthwise residual on kv2 -> kv3 ----------------
__global__ void k_lc(const float* __restrict__ kv2, const float* __restrict__ lc_w,
                     const float* __restrict__ lc_b, float* __restrict__ kv3){
  int c=blockIdx.x&63;
  __shared__ float pl[196];
  for (int p=threadIdx.x;p<196;p+=256) pl[p]=kv2[(size_t)blockIdx.x*196+p];
  __syncthreads();
  int t=threadIdx.x;
  if (t<196){
    int oy=t/14, ox=t%14; float acc=lc_b[c]+pl[t];
    #pragma unroll
    for(int i=0;i<3;i++){int yy=oy+i-1; if((unsigned)yy<14u){
      #pragma unroll
      for(int j=0;j<3;j++){int xx=ox+j-1; if((unsigned)xx<14u) acc+=pl[yy*14+xx]*lc_w[c*9+i*3+j];}}}
    kv3[(size_t)blockIdx.x*196+t]=acc;
  }
}

// ---------------- K5c: kv pointwise 64->128, chunked (b x {K,V} x 7 m-chunks of 28) ---------
__global__ void k_kv(const float* __restrict__ kv3, const float* __restrict__ kv_w,
                     const float* __restrict__ kv_b, unsigned* __restrict__ kbf,
                     unsigned* __restrict__ vbf){
  __shared__ float s[64*28];
  __shared__ float wl[64*64];
  int bid = blockIdx.x;
  int b = bid/14, rem = bid%14;
  int half = rem/7, mc = rem%7;
  int m0 = mc*28;
  int tid = threadIdx.x;
  for (int i=tid;i<1792;i+=256){ int c=i/28, j=i%28;
    s[i] = kv3[((size_t)(b*64)+c)*196 + m0 + j]; }
  for (int j=tid;j<1024;j+=256)
    ((float4*)wl)[j] = ((const float4*)(kv_w + half*4096))[j];
  __syncthreads();
  if (half==0){
    for (int idx=tid; idx<896; idx+=256){
      int mloc = idx%28, o2 = idx/28; int m = m0 + mloc; int o = 2*o2;
      float acc0=kv_b[o], acc1=kv_b[o+1];
      #pragma unroll 8
      for (int c2=0;c2<64;c2++){ float v=s[c2*28+mloc];
        acc0+=v*wl[o*64+c2]; acc1+=v*wl[(o+1)*64+c2]; }
      int h=o2>>4, d2=o2&15;
      kbf[((size_t)(b*2+h)*208 + m)*16 + d2] = pack_bf16(acc0, acc1);
    }
    if (mc==6){
      for (int i=tid;i<384;i+=256){ int h=i/192, r=i%192, m=196+(r>>4), d2=r&15;
        kbf[((size_t)(b*2+h)*208 + m)*16 + d2] = 0; }
    }
  } else {
    for (int idx=tid; idx<896; idx+=256){
      int vo = idx/14, m2l = idx%14; int m2 = mc*14 + m2l; int m = 2*m2;
      int o = 64+vo; int mloc = m - m0;
      float acc0=kv_b[o], acc1=kv_b[o];
      #pragma unroll 8
      for (int c2=0;c2<64;c2++){ float w=wl[vo*64+c2];
        acc0+=s[c2*28+mloc]*w; acc1+=s[c2*28+mloc+1]*w; }
      int h=vo>>5, d=vo&31, dh=d>>4, dd=d&15;
      int s_=m>>5, rm=m&31, g=rm>>3, ip=(rm&7)>>1;
      vbf[(((size_t)(b*2+h)*14 + dh*7 + s_)*64 + g*16 + dd)*4 + ip] = pack_bf16(acc0, acc1);
    }
    if (mc==6){
      for (int idx=tid; idx<896; idx+=256){
        int vo = idx/14, m2l = idx%14; int m = 2*(98+m2l);
        int h=vo>>5, d=vo&31, dh=d>>4, dd=d&15;
        int s_=m>>5, rm=m&31, g=rm>>3, ip=(rm&7)>>1;
        vbf[(((size_t)(b*2+h)*14 + dh*7 + s_)*64 + g*16 + dd)*4 + ip] = 0;
      }
    }
  }
}

// ---------------- K6: MFMA attention v3 — per-lane ds_write_b16 P-pack ----------------
__global__ __launch_bounds__(256,4) void k_attn(const unsigned* __restrict__ qbf,
                       const unsigned* __restrict__ kbf, const unsigned* __restrict__ vbf,
                       const float* __restrict__ rpe, unsigned* __restrict__ ybf){
  __shared__ unsigned SMEM[4*16*116];
  int bh = blockIdx.x & 127, tile = blockIdx.x >> 7;
  int b=bh>>1, h=bh&1, n0=tile*64, tid=threadIdx.x;
  int wv = tid>>6, l = tid&63, g = l>>4, c = l&15, qr = wv*16;

  bf16x8 qa = *(const bf16x8*)(qbf + ((size_t)bh*NPIX + n0+qr+c)*16 + 4*g);

  const float* rp = rpe + ((size_t)(h*NPIX + n0 + qr))*196;
  f32x4 acc[13];
  #pragma unroll
  for (int mt=0; mt<12; mt++){
    #pragma unroll
    for (int r=0;r<4;r++) acc[mt][r] = rp[(size_t)(4*g+r)*196 + mt*16 + c];
  }
  {
    bool v = (c<4);
    #pragma unroll
    for (int r=0;r<4;r++) acc[12][r] = v ? rp[(size_t)(4*g+r)*196 + 192 + c] : -1e30f;
  }
  const unsigned* kB = kbf + (size_t)bh*208*16;
  #pragma unroll
  for (int mt=0; mt<13; mt++){
    bf16x8 kb = *(const bf16x8*)(kB + ((size_t)(mt*16 + c))*16 + 4*g);
    acc[mt] = __builtin_amdgcn_mfma_f32_16x16x32_bf16(qa, kb, acc[mt], 0,0,0);
  }
  float inv[4];
  #pragma unroll
  for (int r=0;r<4;r++){
    float sm = 0.f;
    #pragma unroll
    for (int mt=0;mt<13;mt++){ float e = __expf(acc[mt][r]); acc[mt][r]=e; sm += e; }
    #pragma unroll
    for (int o=1;o<16;o<<=1) sm += __shfl_xor(sm,o);
    inv[r] = 1.f/sm;
  }
  // per-lane bf16 short store: short idx = row*232 + key (key = mt*16+c)
  short* Pw16 = (short*)(SMEM + wv*1856);
  #pragma unroll
  for (int mt=0;mt<13;mt++){
    #pragma unroll
    for (int r=0;r<4;r++){
      unsigned pk = cvt_pk_bf16(acc[mt][r], acc[mt][r]);
      Pw16[(4*g+r)*232 + mt*16 + c] = (short)pk;
    }
  }
  unsigned* Pw = SMEM + wv*1856;
  #pragma unroll
  for (int i=0;i<2;i++){ int row=(l>>3)+8*i, cc=l&7; Pw[row*116 + 104 + cc] = 0; }
  const short* PsS = (const short*)Pw;
  const unsigned* vB = vbf + (size_t)bh*3584;
  f32x4 o0 = {0.f,0.f,0.f,0.f}, o1 = {0.f,0.f,0.f,0.f};
  #pragma unroll
  for (int s=0;s<7;s++){
    bf16x8 pa = *(const bf16x8*)(PsS + c*232 + s*32 + 8*g);
    bf16x8 v0 = *(const bf16x8*)(vB + ((size_t)(s*64 + l))*4);
    bf16x8 v1 = *(const bf16x8*)(vB + ((size_t)((7+s)*64 + l))*4);
    o0 = __builtin_amdgcn_mfma_f32_16x16x32_bf16(pa, v0, o0, 0,0,0);
    o1 = __builtin_amdgcn_mfma_f32_16x16x32_bf16(pa, v1, o1, 0,0,0);
  }
  __syncthreads();
  float* Os = (float*)SMEM;
  #pragma unroll
  for (int r=0;r<4;r++){
    Os[(qr + 4*g + r)*33 + c]      = o0[r]*inv[r];
    Os[(qr + 4*g + r)*33 + 16 + c] = o1[r]*inv[r];
  }
  __syncthreads();
  size_t base = ((size_t)(b*64 + 32 + h*16))*NPIX;
  for (int i=tid;i<1024;i+=256){ int d2=i>>6, rr=i&63;
    unsigned pk = cvt_pk_bf16(Os[rr*33 + 2*d2], Os[rr*33 + 2*d2 + 1]);
    ybf[base + (size_t)d2*NPIX + n0 + rr] = pk; }
}

// ---------------- K7: 3x3 depthwise p1 (2 ch/block) on packed ybf -> packed z1p -------------
__global__ void k_p1(const unsigned* __restrict__ ybf, const float* __restrict__ p1_w,
                     const float* __restrict__ p1_b, const float* __restrict__ p1_g,
                     const float* __restrict__ p1_bb, unsigned* __restrict__ z1p){
  __shared__ float YS[2*NPIX];
  int b = blockIdx.x>>6, cp = blockIdx.x&63;
  int c0 = 2*cp;
  int tid = threadIdx.x;
  const uint4* yp4 = (const uint4*)(ybf + ((size_t)(b*64+cp))*NPIX);
  for (int i=tid;i<784;i+=256){
    uint4 v = yp4[i];
    int p = i*4;
    YS[p+0]=bf16lo(v.x); YS[NPIX+p+0]=bf16hi(v.x);
    YS[p+1]=bf16lo(v.y); YS[NPIX+p+1]=bf16hi(v.y);
    YS[p+2]=bf16lo(v.z); YS[NPIX+p+2]=bf16hi(v.z);
    YS[p+3]=bf16lo(v.w); YS[NPIX+p+3]=bf16hi(v.w);
  }
  float pw_a[9], pw_b[9];
  #pragma unroll
  for (int k=0;k<9;k++){ pw_a[k]=p1_w[c0*9+k]; pw_b[k]=p1_w[(c0+1)*9+k]; }
  float pbA=p1_b[c0], pgA=p1_g[c0], pbbA=p1_bb[c0];
  float pbB=p1_b[c0+1], pgB=p1_g[c0+1], pbbB=p1_bb[c0+1];
  __syncthreads();
  unsigned* zp = z1p + ((size_t)(b*64+cp))*NPIX;
  for (int p4=tid;p4<784;p4+=256){
    int h=p4/14, w0=(p4%14)*4;
    unsigned pk[4];
    #pragma unroll
    for (int j=0;j<4;j++){
      int w=w0+j; float aA=pbA, aB=pbB;
      #pragma unroll
      for (int i=0;i<3;i++){ int hh=h+i-1; if((unsigned)hh<56u){
        #pragma unroll
        for(int jj=0;jj<3;jj++){ int ww=w+jj-1; if((unsigned)ww<56u){
          aA += YS[hh*56+ww]*pw_a[i*3+jj];
          aB += YS[NPIX+hh*56+ww]*pw_b[i*3+jj]; } } } }
      pk[j] = pack_bf16(gelu_f(aA)*pgA+pbbA, gelu_f(aB)*pgB+pbbB);
    }
    uint4 res = {pk[0],pk[1],pk[2],pk[3]};
    *(uint4*)(zp + h*56 + w0) = res;
  }
}

// ---------------- K8: MFMA pointwise 128->16->128 + residual (packed y, z1p prefetch) -------
__global__ __launch_bounds__(256) void k_p23m(const unsigned* __restrict__ z1p, const unsigned* __restrict__ ybf,
                      const float* __restrict__ p2_w, const float* __restrict__ p2_b,
                      const float* __restrict__ p2_g, const float* __restrict__ p2_bb,
                      const float* __restrict__ p3_w, const float* __restrict__ p3_b,
                      const float* __restrict__ p3_g, const float* __restrict__ p3_bb,
                      float* __restrict__ out){
  __shared__ unsigned W2F[4*64*4];
  __shared__ unsigned W3F[8*64*4];
  __shared__ unsigned T16[4][16*12];
  int tid = threadIdx.x;
  int w = tid>>6, l = tid&63, g = l>>4, li = l&15;
  int b = blockIdx.x/49, t = blockIdx.x%49;
  int px0 = t*64 + w*16;
  int px = px0 + li;
  // prefetch A-operands (z1p) BEFORE weight staging so latency hides under it
  const unsigned* zb = z1p + ((size_t)(b*64))*NPIX + px;
  unsigned Au[4][4];
  #pragma unroll
  for (int s=0;s<4;s++){
    #pragma unroll
    for (int j=0;j<4;j++) Au[s][j] = zb[(size_t)(16*s + 4*g + j)*NPIX];
  }
  for (int j=tid;j<1024;j+=256){
    int s=j>>8, ll=(j>>2)&63, e2=j&3;
    int i=ll&15, c=32*s+8*(ll>>4)+2*e2;
    W2F[j] = pack_bf16(p2_w[i*128+c], p2_w[i*128+c+1]);
  }
  for (int j=tid;j<2048;j+=256){
    int grp=j>>8, ll=(j>>2)&63, e2=j&3;
    int gg=ll>>4, o=grp*16+(ll&15);
    unsigned v=0u;
    if (gg<2){ int k=8*gg+2*e2; float g3=p3_g[o];
      v = pack_bf16(p3_w[o*16+k]*g3, p3_w[o*16+k+1]*g3); }
    W3F[j]=v;
  }
  __syncthreads();
  float pb = p2_b[li];
  f32x4 acc; acc[0]=pb; acc[1]=pb; acc[2]=pb; acc[3]=pb;
  #pragma unroll
  for (int s=0;s<4;s++){
    union { unsigned u[4]; bf16x8 v; } A;
    A.u[0]=Au[s][0]; A.u[1]=Au[s][1]; A.u[2]=Au[s][2]; A.u[3]=Au[s][3];
    bf16x8 Bf = *(const bf16x8*)(W2F + (s*64 + l)*4);
    acc = __builtin_amdgcn_mfma_f32_16x16x32_bf16(A.v, Bf, acc, 0,0,0);
  }
  float g2v = p2_g[li], bb2 = p2_bb[li];
  unsigned* tw = &T16[w][0];
  #pragma unroll
  for (int r=0;r<4;r++){
    float tv = gelu_f(acc[r])*g2v + bb2;
    float other = __shfl_xor(tv, 1);
    unsigned pk = cvt_pk_bf16(tv, other);
    if ((l&1)==0) tw[(4*g + r)*12 + (li>>1)] = pk;
  }
  bf16x8 Af3 = {0,0,0,0,0,0,0,0};
  if (g<2){
    union { unsigned u[4]; bf16x8 v; } T;
    const unsigned* tr = tw + li*12 + 4*g;
    T.u[0]=tr[0]; T.u[1]=tr[1]; T.u[2]=tr[2]; T.u[3]=tr[3];
    Af3 = T.v;
  }
  int par = li & 1;
  #pragma unroll
  for (int grp=0; grp<8; grp++){
    int o = grp*16 + li;
    float b3 = p3_b[o]*p3_g[o] + p3_bb[o];
    size_t poff = ((size_t)(b*64 + (o>>1)))*NPIX + px0 + 4*g;
    uint4 yv4 = *(const uint4*)(ybf + poff);
    float y0,y1,y2,y3;
    if (par){ y0=bf16hi(yv4.x); y1=bf16hi(yv4.y); y2=bf16hi(yv4.z); y3=bf16hi(yv4.w); }
    else    { y0=bf16lo(yv4.x); y1=bf16lo(yv4.y); y2=bf16lo(yv4.z); y3=bf16lo(yv4.w); }
    f32x4 c2; c2[0]=y0+b3; c2[1]=y1+b3; c2[2]=y2+b3; c2[3]=y3+b3;
    bf16x8 Bf3 = *(const bf16x8*)(W3F + (grp*64+l)*4);
    c2 = __builtin_amdgcn_mfma_f32_16x16x32_bf16(Af3, Bf3, c2, 0,0,0);
    float4 res = {c2[0],c2[1],c2[2],c2[3]};
    *(float4*)(out + ((size_t)(b*128+o))*NPIX + px0 + 4*g) = res;
  }
}

// ---------------- launch ----------------
extern "C" void kernel_launch(void* const* d_in, const int* in_sizes, int n_in,
                              void* d_out, int out_size, void* d_ws, size_t ws_size,
                              hipStream_t stream) {
  (void)in_sizes; (void)n_in; (void)out_size; (void)ws_size;
  const float* x       = (const float*)d_in[0];
  const float* rpe     = (const float*)d_in[1];
  const float* dc_w    = (const float*)d_in[2];
  const float* dc_b    = (const float*)d_in[3];
  const float* dcp1_w  = (const float*)d_in[4];
  const float* dcp1_g  = (const float*)d_in[5];
  const float* dcp1_b  = (const float*)d_in[6];
  const float* dcp2_w  = (const float*)d_in[7];
  const float* dcp2_b  = (const float*)d_in[8];
  const float* q_w     = (const float*)d_in[9];
  const float* q_b     = (const float*)d_in[10];
  const float* kv_w    = (const float*)d_in[11];
  const float* kv_b    = (const float*)d_in[12];
  const float* sr1_w   = (const float*)d_in[13];
  const float* sr1_g   = (const float*)d_in[14];
  const float* sr1_b   = (const float*)d_in[15];
  const float* sr2_w   = (const float*)d_in[16];
  const float* sr2_g   = (const float*)d_in[17];
  const float* sr2_b   = (const float*)d_in[18];
  const float* lc_w    = (const float*)d_in[19];
  const float* lc_b    = (const float*)d_in[20];
  const float* p1_w    = (const float*)d_in[21];
  const float* p1_b    = (const float*)d_in[22];
  const float* p1_g    = (const float*)d_in[23];
  const float* p1_bb   = (const float*)d_in[24];
  const float* p2_w    = (const float*)d_in[25];
  const float* p2_b    = (const float*)d_in[26];
  const float* p2_g    = (const float*)d_in[27];
  const float* p2_bb   = (const float*)d_in[28];
  const float* p3_w    = (const float*)d_in[29];
  const float* p3_b    = (const float*)d_in[30];
  const float* p3_g    = (const float*)d_in[31];
  const float* p3_bb   = (const float*)d_in[32];
  float* out = (float*)d_out;
  float* ws  = (float*)d_ws;

  const size_t OFF_Y     = 0;           // ybf: 12.85M dwords (packed bf16 pairs)
  const size_t OFF_A     = 25690112;    // qbf (6.42M dwords)
  const size_t OFF_Z1P   = 25690112 + 6422528;  // z1p: 12.85M dwords
  const size_t OFF_POOL  = 54591488;
  const size_t OFF_XMEAN = 54628352;
  const size_t OFF_W     = 54632448;
  const size_t OFF_DB    = 54669312;
  const size_t OFF_KV2   = 54673408;
  const size_t OFF_KV3   = 55476224;
  const size_t OFF_K     = 56279040;
  const size_t OFF_V     = 57081856;

  unsigned* ybf   = (unsigned*)(ws + OFF_Y);
  unsigned* qbf   = (unsigned*)(ws + OFF_A);
  unsigned* z1p   = (unsigned*)(ws + OFF_Z1P);
  float*    pool  = ws + OFF_POOL;
  float*    xmean = ws + OFF_XMEAN;
  float*    wgt   = ws + OFF_W;
  float*    dbias = ws + OFF_DB;
  float*    kv2   = ws + OFF_KV2;
  float*    kv3   = ws + OFF_KV3;
  unsigned* kbf   = (unsigned*)(ws + OFF_K);
  unsigned* vbf   = (unsigned*)(ws + OFF_V);

  k_pool  <<<4096, 64, 0, stream>>>(x, pool, xmean);
  k_dcproj<<<64, 256, 0, stream>>>(pool, xmean, dcp1_w, dcp1_g, dcp1_b, dcp2_w, dcp2_b, dc_w, dc_b, wgt, dbias);
  k_y1    <<<2048, 256, 0, stream>>>(x, wgt, dbias, ybf);
  k_qproj <<<3136, 256, 0, stream>>>(x, q_w, q_b, qbf);
  k_sr    <<<4096, 256, 0, stream>>>(x, sr1_w, sr1_g, sr1_b, sr2_w, sr2_g, sr2_b, kv2);
  k_lc    <<<4096, 256, 0, stream>>>(kv2, lc_w, lc_b, kv3);
  k_kv    <<<896, 256, 0, stream>>>(kv3, kv_w, kv_b, kbf, vbf);
  k_attn  <<<6272, 256, 0, stream>>>(qbf, kbf, vbf, rpe, ybf);
  k_p1    <<<4096, 256, 0, stream>>>(ybf, p1_w, p1_b, p1_g, p1_bb, z1p);
  k_p23m  <<<3136, 256, 0, stream>>>(z1p, ybf, p2_w, p2_b, p2_g, p2_bb, p3_w, p3_b, p3_g, p3_bb, out);
}

// Round 17
// 270.371 us; speedup vs baseline: 1.0192x; 1.0192x over previous
//
#include <hip/hip_runtime.h>
#include <cstddef>

// Shapes: B=64, C=128, Ch=64, H=W=56, N=3136, G=2, K=3, heads=2, hd=32, Nk=196, inner=16
#define NPIX 3136

typedef __attribute__((ext_vector_type(8))) short bf16x8;
typedef __attribute__((ext_vector_type(4))) float f32x4;

__device__ __forceinline__ float gelu_f(float x){
  return 0.5f*x*(1.0f+erff(x*0.70710678118654752440f));
}

__device__ __forceinline__ unsigned pack_bf16(float a, float b){
  unsigned ua = __float_as_uint(a), ub = __float_as_uint(b);
  ua = (ua + 0x7FFFu + ((ua>>16)&1u)) >> 16;
  ub = (ub + 0x7FFFu + ((ub>>16)&1u)) >> 16;
  return ua | (ub<<16);
}

__device__ __forceinline__ unsigned cvt_pk_bf16(float a, float b){
  unsigned r;
  asm("v_cvt_pk_bf16_f32 %0, %1, %2" : "=v"(r) : "v"(a), "v"(b));
  return r;
}

__device__ __forceinline__ float bf16lo(unsigned u){ return __uint_as_float(u<<16); }
__device__ __forceinline__ float bf16hi(unsigned u){ return __uint_as_float(u & 0xFFFF0000u); }

// ---------------- K1: adaptive_avg_pool(3x3, overlapping) + full mean, float4 loads ----------
__global__ void k_pool(const float* __restrict__ x, float* __restrict__ pooled, float* __restrict__ xmean){
  int b = blockIdx.x >> 6, c = blockIdx.x & 63;
  const float4* xp = (const float4*)(x + ((size_t)(b*128 + c))*NPIX);
  float r[9] = {0,0,0,0,0,0,0,0,0};
  float tot = 0.f;
  for (int p4 = threadIdx.x; p4 < 784; p4 += 64){
    float4 v4 = xp[p4];
    int p = p4*4;
    int h = p/56, w0 = p%56;
    bool h0 = (h<=18), h1 = (h>=18 && h<=37), h2 = (h>=37);
    float vv[4] = {v4.x, v4.y, v4.z, v4.w};
    #pragma unroll
    for (int j=0;j<4;j++){
      int w = w0+j; float v = vv[j];
      tot += v;
      bool b0 = (w<=18), b1 = (w>=18 && w<=37), b2 = (w>=37);
      if(h0){ if(b0) r[0]+=v; if(b1) r[1]+=v; if(b2) r[2]+=v; }
      if(h1){ if(b0) r[3]+=v; if(b1) r[4]+=v; if(b2) r[5]+=v; }
      if(h2){ if(b0) r[6]+=v; if(b1) r[7]+=v; if(b2) r[8]+=v; }
    }
  }
  #pragma unroll
  for (int o=32;o>0;o>>=1){
    #pragma unroll
    for (int k=0;k<9;k++) r[k]+=__shfl_xor(r[k],o);
    tot += __shfl_xor(tot,o);
  }
  if (threadIdx.x==0){
    const float cs[3]={19.f,20.f,19.f};
    #pragma unroll
    for(int i=0;i<3;i++)
      #pragma unroll
      for(int j=0;j<3;j++)
        pooled[(size_t)blockIdx.x*9 + i*3+j] = r[i*3+j]/(cs[i]*cs[j]);
    xmean[blockIdx.x] = tot*(1.f/3136.f);
  }
}

// ---------------- K2: dc_proj + softmax over G; build weight + dyn_bias ----
__global__ void k_dcproj(const float* __restrict__ pooled, const float* __restrict__ xmean,
    const float* __restrict__ dcp1_w, const float* __restrict__ dcp1_g, const float* __restrict__ dcp1_b,
    const float* __restrict__ dcp2_w, const float* __restrict__ dcp2_b,
    const float* __restrict__ dc_w, const float* __restrict__ dc_b,
    float* __restrict__ weightO, float* __restrict__ dyn_bias){
  int b = blockIdx.x; int tid = threadIdx.x;
  __shared__ float sp[576], sm[64], t1[144], t1b[16], s2[1152], s2b[128];
  for (int i=tid;i<576;i+=256) sp[i]=pooled[(size_t)b*576+i];
  if (tid<64) sm[tid]=xmean[b*64+tid];
  __syncthreads();
  for (int idx=tid; idx<160; idx+=256){
    if (idx<144){
      int o=idx/9, pos=idx%9; float s=0.f;
      for(int c2=0;c2<64;c2++) s += sp[c2*9+pos]*dcp1_w[o*64+c2];
      t1[idx]=gelu_f(s*dcp1_g[o]+dcp1_b[o]);
    } else {
      int o=idx-144; float s=0.f;
      for(int c2=0;c2<64;c2++) s+=sm[c2]*dcp1_w[o*64+c2];
      t1b[o]=gelu_f(s*dcp1_g[o]+dcp1_b[o]);
    }
  }
  __syncthreads();
  for (int idx=tid; idx<1280; idx+=256){
    if (idx<1152){
      int o=idx/9,pos=idx%9; float s=dcp2_b[o];
      #pragma unroll
      for(int i=0;i<16;i++) s+=t1[i*9+pos]*dcp2_w[o*16+i];
      s2[idx]=s;
    } else {
      int o=idx-1152; float s=dcp2_b[o];
      #pragma unroll
      for(int i=0;i<16;i++) s+=t1b[i]*dcp2_w[o*16+i];
      s2b[o]=s;
    }
  }
  __syncthreads();
  for (int idx=tid; idx<640; idx+=256){
    if (idx<576){
      int ch=idx/9, pos=idx%9;
      float a=s2[ch*9+pos], bb=s2[(64+ch)*9+pos];
      float m=fmaxf(a,bb); float e0=expf(a-m), e1=expf(bb-m); float w0=e0/(e0+e1);
      weightO[(size_t)b*576+idx] = w0*dc_w[ch*9+pos] + (1.f-w0)*dc_w[576+ch*9+pos];
    } else {
      int ch=idx-576;
      float a=s2b[ch], bb=s2b[64+ch];
      float m=fmaxf(a,bb); float e0=expf(a-m), e1=expf(bb-m); float w0=e0/(e0+e1);
      dyn_bias[b*64+ch] = w0*dc_b[ch] + (1.f-w0)*dc_b[64+ch];
    }
  }
}

// ---------------- K3: dynamic dw 3x3 on x1, 2 ch/block -> packed bf16 pair dwords ybf -------
__global__ void k_y1(const float* __restrict__ x, const float* __restrict__ weightO,
                     const float* __restrict__ dyn_bias, unsigned* __restrict__ ybf){
  __shared__ float XS[2*NPIX];
  int b = blockIdx.x>>5, cp = blockIdx.x&31;
  int c0 = 2*cp;
  int tid = threadIdx.x;
  const float4* xp0 = (const float4*)(x + ((size_t)(b*128+c0))*NPIX);
  const float4* xp1 = (const float4*)(x + ((size_t)(b*128+c0+1))*NPIX);
  float4* XS4 = (float4*)XS;
  for (int i=tid;i<784;i+=256){ XS4[i]=xp0[i]; XS4[784+i]=xp1[i]; }
  float w9a[9], w9b[9];
  #pragma unroll
  for (int k=0;k<9;k++){ w9a[k]=weightO[((size_t)(b*64+c0))*9+k]; w9b[k]=weightO[((size_t)(b*64+c0+1))*9+k]; }
  float biasA = dyn_bias[b*64+c0], biasB = dyn_bias[b*64+c0+1];
  __syncthreads();
  unsigned* yp = ybf + ((size_t)(b*64+cp))*NPIX;
  for (int p4=tid;p4<784;p4+=256){
    int h=p4/14, w0=(p4%14)*4;
    unsigned pk[4];
    #pragma unroll
    for (int j=0;j<4;j++){
      int w=w0+j; float aA=biasA, aB=biasB;
      #pragma unroll
      for (int i=0;i<3;i++){ int hh=h+i-1; if((unsigned)hh<56u){
        #pragma unroll
        for(int jj=0;jj<3;jj++){ int ww=w+jj-1; if((unsigned)ww<56u){
          aA += XS[hh*56+ww]*w9a[i*3+jj];
          aB += XS[NPIX+hh*56+ww]*w9b[i*3+jj]; } } } }
      pk[j] = pack_bf16(aA, aB);
    }
    uint4 res = {pk[0],pk[1],pk[2],pk[3]};
    *(uint4*)(yp + h*56 + w0) = res;
  }
}

// ---------------- K4: q projection -> packed bf16 rows, PRE-SCALED by 1/sqrt(32) ------------
__global__ void k_qproj(const float* __restrict__ x, const float* __restrict__ q_w,
                        const float* __restrict__ q_b, unsigned* __restrict__ qbf){
  int b = blockIdx.x/49, t = blockIdx.x%49; int n0 = t*64; int tid = threadIdx.x;
  __shared__ float qwT[64*64]; // [c][o]
  __shared__ float xt[64*64];  // [c][p]
  for (int i4=tid; i4<1024; i4+=256){ int o=i4>>4, c4=(i4&15)*4;
    float4 w4 = *(const float4*)(q_w + o*64 + c4);
    qwT[(c4+0)*64+o]=w4.x; qwT[(c4+1)*64+o]=w4.y; qwT[(c4+2)*64+o]=w4.z; qwT[(c4+3)*64+o]=w4.w; }
  for (int i4=tid; i4<1024; i4+=256){ int c2=i4>>4, p4=(i4&15)*4;
    float4 v4 = *(const float4*)(x + ((size_t)(b*128+64+c2))*NPIX + n0 + p4);
    *(float4*)(xt + c2*64 + p4) = v4; }
  __syncthreads();
  int d2_ = tid&31, prow = tid>>5;
  int o0 = 2*d2_; int h = d2_>>4, dd = d2_&15;
  float b0 = q_b[o0], b1 = q_b[o0+1];
  float a0[8], a1[8];
  #pragma unroll
  for (int i=0;i<8;i++){ a0[i]=b0; a1[i]=b1; }
  #pragma unroll 4
  for (int c2=0;c2<64;c2++){
    float w0 = qwT[c2*64+o0], w1 = qwT[c2*64+o0+1];
    #pragma unroll
    for (int i=0;i<8;i++){ float xv = xt[c2*64 + prow*8 + i]; a0[i]+=xv*w0; a1[i]+=xv*w1; }
  }
  const float sc = 0.17677669529663687f; // 1/sqrt(32), folded into Q
  #pragma unroll
  for (int i=0;i<8;i++)
    qbf[((size_t)(b*2+h)*NPIX + n0 + prow*8 + i)*16 + dd] = pack_bf16(a0[i]*sc, a1[i]*sc);
}

// ---------------- K5a: fused 7x7 s4 p3 dw + BN/GELU + sr2 BN + 3x3 dw residual -> kv3 -------
// grid: B*64 (b,c), block 256. Phase1: stage x2 channel, compute kv2 (196) into LDS.
// Phase2 (after barrier): 3x3 depthwise residual on the LDS kv2 -> kv3. Saves the kv2
// global roundtrip + the separate k_lc launch.
__global__ void k_srlc(const float* __restrict__ x, const float* __restrict__ sr1_w,
                     const float* __restrict__ sr1_g, const float* __restrict__ sr1_b,
                     const float* __restrict__ sr2_w, const float* __restrict__ sr2_g,
                     const float* __restrict__ sr2_b, const float* __restrict__ lc_w,
                     const float* __restrict__ lc_b, float* __restrict__ kv3){
  int b=blockIdx.x>>6, c=blockIdx.x&63;
  __shared__ float pl[NPIX];
  __shared__ float k2[196];
  const float4* xp4 = (const float4*)(x + ((size_t)(b*128+64+c))*NPIX);
  float4* pl4 = (float4*)pl;
  for (int i=threadIdx.x;i<784;i+=256) pl4[i]=xp4[i];
  __syncthreads();
  int t=threadIdx.x;
  if (t<196){
    int oy=t/14, ox=t%14;
    float acc=0.f;
    #pragma unroll
    for(int i=0;i<7;i++){ int yy=oy*4-3+i; if((unsigned)yy<56u){
      #pragma unroll
      for(int j=0;j<7;j++){ int xx=ox*4-3+j; if((unsigned)xx<56u) acc += pl[yy*56+xx]*sr1_w[c*49+i*7+j]; } } }
    float g = gelu_f(acc*sr1_g[c]+sr1_b[c]);
    k2[t] = (g*sr2_w[c])*sr2_g[c]+sr2_b[c];
  }
  __syncthreads();
  if (t<196){
    int oy=t/14, ox=t%14; float acc=lc_b[c]+k2[t];
    #pragma unroll
    for(int i=0;i<3;i++){int yy=oy+i-1; if((unsigned)yy<14u){
      #pragma unroll
      for(int j=0;j<3;j++){int xx=ox+j-1; if((unsigned)xx<14u) acc+=k2[yy*14+xx]*lc_w[c*9+i*3+j];}}}
    kv3[(size_t)blockIdx.x*196+t]=acc;
  }
}

// ---------------- K5c: kv pointwise 64->128, chunked (b x {K,V} x 7 m-chunks of 28) ---------
__global__ void k_kv(const float* __restrict__ kv3, const float* __restrict__ kv_w,
                     const float* __restrict__ kv_b, unsigned* __restrict__ kbf,
                     unsigned* __restrict__ vbf){
  __shared__ float s[64*28];
  __shared__ float wl[64*64];
  int bid = blockIdx.x;
  int b = bid/14, rem = bid%14;
  int half = rem/7, mc = rem%7;
  int m0 = mc*28;
  int tid = threadIdx.x;
  for (int i=tid;i<1792;i+=256){ int c=i/28, j=i%28;
    s[i] = kv3[((size_t)(b*64)+c)*196 + m0 + j]; }
  for (int j=tid;j<1024;j+=256)
    ((float4*)wl)[j] = ((const float4*)(kv_w + half*4096))[j];
  __syncthreads();
  if (half==0){
    for (int idx=tid; idx<896; idx+=256){
      int mloc = idx%28, o2 = idx/28; int m = m0 + mloc; int o = 2*o2;
      float acc0=kv_b[o], acc1=kv_b[o+1];
      #pragma unroll 8
      for (int c2=0;c2<64;c2++){ float v=s[c2*28+mloc];
        acc0+=v*wl[o*64+c2]; acc1+=v*wl[(o+1)*64+c2]; }
      int h=o2>>4, d2=o2&15;
      kbf[((size_t)(b*2+h)*208 + m)*16 + d2] = pack_bf16(acc0, acc1);
    }
    if (mc==6){
      for (int i=tid;i<384;i+=256){ int h=i/192, r=i%192, m=196+(r>>4), d2=r&15;
        kbf[((size_t)(b*2+h)*208 + m)*16 + d2] = 0; }
    }
  } else {
    for (int idx=tid; idx<896; idx+=256){
      int vo = idx/14, m2l = idx%14; int m2 = mc*14 + m2l; int m = 2*m2;
      int o = 64+vo; int mloc = m - m0;
      float acc0=kv_b[o], acc1=kv_b[o];
      #pragma unroll 8
      for (int c2=0;c2<64;c2++){ float w=wl[vo*64+c2];
        acc0+=s[c2*28+mloc]*w; acc1+=s[c2*28+mloc+1]*w; }
      int h=vo>>5, d=vo&31, dh=d>>4, dd=d&15;
      int s_=m>>5, rm=m&31, g=rm>>3, ip=(rm&7)>>1;
      vbf[(((size_t)(b*2+h)*14 + dh*7 + s_)*64 + g*16 + dd)*4 + ip] = pack_bf16(acc0, acc1);
    }
    if (mc==6){
      for (int idx=tid; idx<896; idx+=256){
        int vo = idx/14, m2l = idx%14; int m = 2*(98+m2l);
        int h=vo>>5, d=vo&31, dh=d>>4, dd=d&15;
        int s_=m>>5, rm=m&31, g=rm>>3, ip=(rm&7)>>1;
        vbf[(((size_t)(b*2+h)*14 + dh*7 + s_)*64 + g*16 + dd)*4 + ip] = 0;
      }
    }
  }
}

// ---------------- K6: MFMA attention v3 — per-lane ds_write_b16 P-pack ----------------
__global__ __launch_bounds__(256,4) void k_attn(const unsigned* __restrict__ qbf,
                       const unsigned* __restrict__ kbf, const unsigned* __restrict__ vbf,
                       const float* __restrict__ rpe, unsigned* __restrict__ ybf){
  __shared__ unsigned SMEM[4*16*116];
  int bh = blockIdx.x & 127, tile = blockIdx.x >> 7;
  int b=bh>>1, h=bh&1, n0=tile*64, tid=threadIdx.x;
  int wv = tid>>6, l = tid&63, g = l>>4, c = l&15, qr = wv*16;

  bf16x8 qa = *(const bf16x8*)(qbf + ((size_t)bh*NPIX + n0+qr+c)*16 + 4*g);

  const float* rp = rpe + ((size_t)(h*NPIX + n0 + qr))*196;
  f32x4 acc[13];
  #pragma unroll
  for (int mt=0; mt<12; mt++){
    #pragma unroll
    for (int r=0;r<4;r++) acc[mt][r] = rp[(size_t)(4*g+r)*196 + mt*16 + c];
  }
  {
    bool v = (c<4);
    #pragma unroll
    for (int r=0;r<4;r++) acc[12][r] = v ? rp[(size_t)(4*g+r)*196 + 192 + c] : -1e30f;
  }
  const unsigned* kB = kbf + (size_t)bh*208*16;
  #pragma unroll
  for (int mt=0; mt<13; mt++){
    bf16x8 kb = *(const bf16x8*)(kB + ((size_t)(mt*16 + c))*16 + 4*g);
    acc[mt] = __builtin_amdgcn_mfma_f32_16x16x32_bf16(qa, kb, acc[mt], 0,0,0);
  }
  float inv[4];
  #pragma unroll
  for (int r=0;r<4;r++){
    float sm = 0.f;
    #pragma unroll
    for (int mt=0;mt<13;mt++){ float e = __expf(acc[mt][r]); acc[mt][r]=e; sm += e; }
    #pragma unroll
    for (int o=1;o<16;o<<=1) sm += __shfl_xor(sm,o);
    inv[r] = 1.f/sm;
  }
  short* Pw16 = (short*)(SMEM + wv*1856);
  #pragma unroll
  for (int mt=0;mt<13;mt++){
    #pragma unroll
    for (int r=0;r<4;r++){
      unsigned pk = cvt_pk_bf16(acc[mt][r], acc[mt][r]);
      Pw16[(4*g+r)*232 + mt*16 + c] = (short)pk;
    }
  }
  unsigned* Pw = SMEM + wv*1856;
  #pragma unroll
  for (int i=0;i<2;i++){ int row=(l>>3)+8*i, cc=l&7; Pw[row*116 + 104 + cc] = 0; }
  const short* PsS = (const short*)Pw;
  const unsigned* vB = vbf + (size_t)bh*3584;
  f32x4 o0 = {0.f,0.f,0.f,0.f}, o1 = {0.f,0.f,0.f,0.f};
  #pragma unroll
  for (int s=0;s<7;s++){
    bf16x8 pa = *(const bf16x8*)(PsS + c*232 + s*32 + 8*g);
    bf16x8 v0 = *(const bf16x8*)(vB + ((size_t)(s*64 + l))*4);
    bf16x8 v1 = *(const bf16x8*)(vB + ((size_t)((7+s)*64 + l))*4);
    o0 = __builtin_amdgcn_mfma_f32_16x16x32_bf16(pa, v0, o0, 0,0,0);
    o1 = __builtin_amdgcn_mfma_f32_16x16x32_bf16(pa, v1, o1, 0,0,0);
  }
  __syncthreads();
  float* Os = (float*)SMEM;
  #pragma unroll
  for (int r=0;r<4;r++){
    Os[(qr + 4*g + r)*33 + c]      = o0[r]*inv[r];
    Os[(qr + 4*g + r)*33 + 16 + c] = o1[r]*inv[r];
  }
  __syncthreads();
  size_t base = ((size_t)(b*64 + 32 + h*16))*NPIX;
  for (int i=tid;i<1024;i+=256){ int d2=i>>6, rr=i&63;
    unsigned pk = cvt_pk_bf16(Os[rr*33 + 2*d2], Os[rr*33 + 2*d2 + 1]);
    ybf[base + (size_t)d2*NPIX + n0 + rr] = pk; }
}

// ---------------- K7: 3x3 depthwise p1 (2 ch/block) on packed ybf -> packed z1p -------------
__global__ void k_p1(const unsigned* __restrict__ ybf, const float* __restrict__ p1_w,
                     const float* __restrict__ p1_b, const float* __restrict__ p1_g,
                     const float* __restrict__ p1_bb, unsigned* __restrict__ z1p){
  __shared__ float YS[2*NPIX];
  int b = blockIdx.x>>6, cp = blockIdx.x&63;
  int c0 = 2*cp;
  int tid = threadIdx.x;
  const uint4* yp4 = (const uint4*)(ybf + ((size_t)(b*64+cp))*NPIX);
  for (int i=tid;i<784;i+=256){
    uint4 v = yp4[i];
    int p = i*4;
    YS[p+0]=bf16lo(v.x); YS[NPIX+p+0]=bf16hi(v.x);
    YS[p+1]=bf16lo(v.y); YS[NPIX+p+1]=bf16hi(v.y);
    YS[p+2]=bf16lo(v.z); YS[NPIX+p+2]=bf16hi(v.z);
    YS[p+3]=bf16lo(v.w); YS[NPIX+p+3]=bf16hi(v.w);
  }
  float pw_a[9], pw_b[9];
  #pragma unroll
  for (int k=0;k<9;k++){ pw_a[k]=p1_w[c0*9+k]; pw_b[k]=p1_w[(c0+1)*9+k]; }
  float pbA=p1_b[c0], pgA=p1_g[c0], pbbA=p1_bb[c0];
  float pbB=p1_b[c0+1], pgB=p1_g[c0+1], pbbB=p1_bb[c0+1];
  __syncthreads();
  unsigned* zp = z1p + ((size_t)(b*64+cp))*NPIX;
  for (int p4=tid;p4<784;p4+=256){
    int h=p4/14, w0=(p4%14)*4;
    unsigned pk[4];
    #pragma unroll
    for (int j=0;j<4;j++){
      int w=w0+j; float aA=pbA, aB=pbB;
      #pragma unroll
      for (int i=0;i<3;i++){ int hh=h+i-1; if((unsigned)hh<56u){
        #pragma unroll
        for(int jj=0;jj<3;jj++){ int ww=w+jj-1; if((unsigned)ww<56u){
          aA += YS[hh*56+ww]*pw_a[i*3+jj];
          aB += YS[NPIX+hh*56+ww]*pw_b[i*3+jj]; } } } }
      pk[j] = pack_bf16(gelu_f(aA)*pgA+pbbA, gelu_f(aB)*pgB+pbbB);
    }
    uint4 res = {pk[0],pk[1],pk[2],pk[3]};
    *(uint4*)(zp + h*56 + w0) = res;
  }
}

// ---------------- K8: MFMA pointwise 128->16->128 + residual (packed y, z1p prefetch) -------
__global__ __launch_bounds__(256) void k_p23m(const unsigned* __restrict__ z1p, const unsigned* __restrict__ ybf,
                      const float* __restrict__ p2_w, const float* __restrict__ p2_b,
                      const float* __restrict__ p2_g, const float* __restrict__ p2_bb,
                      const float* __restrict__ p3_w, const float* __restrict__ p3_b,
                      const float* __restrict__ p3_g, const float* __restrict__ p3_bb,
                      float* __restrict__ out){
  __shared__ unsigned W2F[4*64*4];
  __shared__ unsigned W3F[8*64*4];
  __shared__ unsigned T16[4][16*12];
  int tid = threadIdx.x;
  int w = tid>>6, l = tid&63, g = l>>4, li = l&15;
  int b = blockIdx.x/49, t = blockIdx.x%49;
  int px0 = t*64 + w*16;
  int px = px0 + li;
  const unsigned* zb = z1p + ((size_t)(b*64))*NPIX + px;
  unsigned Au[4][4];
  #pragma unroll
  for (int s=0;s<4;s++){
    #pragma unroll
    for (int j=0;j<4;j++) Au[s][j] = zb[(size_t)(16*s + 4*g + j)*NPIX];
  }
  for (int j=tid;j<1024;j+=256){
    int s=j>>8, ll=(j>>2)&63, e2=j&3;
    int i=ll&15, c=32*s+8*(ll>>4)+2*e2;
    W2F[j] = pack_bf16(p2_w[i*128+c], p2_w[i*128+c+1]);
  }
  for (int j=tid;j<2048;j+=256){
    int grp=j>>8, ll=(j>>2)&63, e2=j&3;
    int gg=ll>>4, o=grp*16+(ll&15);
    unsigned v=0u;
    if (gg<2){ int k=8*gg+2*e2; float g3=p3_g[o];
      v = pack_bf16(p3_w[o*16+k]*g3, p3_w[o*16+k+1]*g3); }
    W3F[j]=v;
  }
  __syncthreads();
  float pb = p2_b[li];
  f32x4 acc; acc[0]=pb; acc[1]=pb; acc[2]=pb; acc[3]=pb;
  #pragma unroll
  for (int s=0;s<4;s++){
    union { unsigned u[4]; bf16x8 v; } A;
    A.u[0]=Au[s][0]; A.u[1]=Au[s][1]; A.u[2]=Au[s][2]; A.u[3]=Au[s][3];
    bf16x8 Bf = *(const bf16x8*)(W2F + (s*64 + l)*4);
    acc = __builtin_amdgcn_mfma_f32_16x16x32_bf16(A.v, Bf, acc, 0,0,0);
  }
  float g2v = p2_g[li], bb2 = p2_bb[li];
  unsigned* tw = &T16[w][0];
  #pragma unroll
  for (int r=0;r<4;r++){
    float tv = gelu_f(acc[r])*g2v + bb2;
    float other = __shfl_xor(tv, 1);
    unsigned pk = cvt_pk_bf16(tv, other);
    if ((l&1)==0) tw[(4*g + r)*12 + (li>>1)] = pk;
  }
  bf16x8 Af3 = {0,0,0,0,0,0,0,0};
  if (g<2){
    union { unsigned u[4]; bf16x8 v; } T;
    const unsigned* tr = tw + li*12 + 4*g;
    T.u[0]=tr[0]; T.u[1]=tr[1]; T.u[2]=tr[2]; T.u[3]=tr[3];
    Af3 = T.v;
  }
  int par = li & 1;
  #pragma unroll
  for (int grp=0; grp<8; grp++){
    int o = grp*16 + li;
    float b3 = p3_b[o]*p3_g[o] + p3_bb[o];
    size_t poff = ((size_t)(b*64 + (o>>1)))*NPIX + px0 + 4*g;
    uint4 yv4 = *(const uint4*)(ybf + poff);
    float y0,y1,y2,y3;
    if (par){ y0=bf16hi(yv4.x); y1=bf16hi(yv4.y); y2=bf16hi(yv4.z); y3=bf16hi(yv4.w); }
    else    { y0=bf16lo(yv4.x); y1=bf16lo(yv4.y); y2=bf16lo(yv4.z); y3=bf16lo(yv4.w); }
    f32x4 c2; c2[0]=y0+b3; c2[1]=y1+b3; c2[2]=y2+b3; c2[3]=y3+b3;
    bf16x8 Bf3 = *(const bf16x8*)(W3F + (grp*64+l)*4);
    c2 = __builtin_amdgcn_mfma_f32_16x16x32_bf16(Af3, Bf3, c2, 0,0,0);
    float4 res = {c2[0],c2[1],c2[2],c2[3]};
    *(float4*)(out + ((size_t)(b*128+o))*NPIX + px0 + 4*g) = res;
  }
}

// ---------------- launch ----------------
extern "C" void kernel_launch(void* const* d_in, const int* in_sizes, int n_in,
                              void* d_out, int out_size, void* d_ws, size_t ws_size,
                              hipStream_t stream) {
  (void)in_sizes; (void)n_in; (void)out_size; (void)ws_size;
  const float* x       = (const float*)d_in[0];
  const float* rpe     = (const float*)d_in[1];
  const float* dc_w    = (const float*)d_in[2];
  const float* dc_b    = (const float*)d_in[3];
  const float* dcp1_w  = (const float*)d_in[4];
  const float* dcp1_g  = (const float*)d_in[5];
  const float* dcp1_b  = (const float*)d_in[6];
  const float* dcp2_w  = (const float*)d_in[7];
  const float* dcp2_b  = (const float*)d_in[8];
  const float* q_w     = (const float*)d_in[9];
  const float* q_b     = (const float*)d_in[10];
  const float* kv_w    = (const float*)d_in[11];
  const float* kv_b    = (const float*)d_in[12];
  const float* sr1_w   = (const float*)d_in[13];
  const float* sr1_g   = (const float*)d_in[14];
  const float* sr1_b   = (const float*)d_in[15];
  const float* sr2_w   = (const float*)d_in[16];
  const float* sr2_g   = (const float*)d_in[17];
  const float* sr2_b   = (const float*)d_in[18];
  const float* lc_w    = (const float*)d_in[19];
  const float* lc_b    = (const float*)d_in[20];
  const float* p1_w    = (const float*)d_in[21];
  const float* p1_b    = (const float*)d_in[22];
  const float* p1_g    = (const float*)d_in[23];
  const float* p1_bb   = (const float*)d_in[24];
  const float* p2_w    = (const float*)d_in[25];
  const float* p2_b    = (const float*)d_in[26];
  const float* p2_g    = (const float*)d_in[27];
  const float* p2_bb   = (const float*)d_in[28];
  const float* p3_w    = (const float*)d_in[29];
  const float* p3_b    = (const float*)d_in[30];
  const float* p3_g    = (const float*)d_in[31];
  const float* p3_bb   = (const float*)d_in[32];
  float* out = (float*)d_out;
  float* ws  = (float*)d_ws;

  const size_t OFF_Y     = 0;           // ybf: 12.85M dwords (packed bf16 pairs)
  const size_t OFF_A     = 25690112;    // qbf (6.42M dwords)
  const size_t OFF_Z1P   = 25690112 + 6422528;  // z1p: 12.85M dwords
  const size_t OFF_POOL  = 54591488;
  const size_t OFF_XMEAN = 54628352;
  const size_t OFF_W     = 54632448;
  const size_t OFF_DB    = 54669312;
  const size_t OFF_KV3   = 55476224;
  const size_t OFF_K     = 56279040;
  const size_t OFF_V     = 57081856;

  unsigned* ybf   = (unsigned*)(ws + OFF_Y);
  unsigned* qbf   = (unsigned*)(ws + OFF_A);
  unsigned* z1p   = (unsigned*)(ws + OFF_Z1P);
  float*    pool  = ws + OFF_POOL;
  float*    xmean = ws + OFF_XMEAN;
  float*    wgt   = ws + OFF_W;
  float*    dbias = ws + OFF_DB;
  float*    kv3   = ws + OFF_KV3;
  unsigned* kbf   = (unsigned*)(ws + OFF_K);
  unsigned* vbf   = (unsigned*)(ws + OFF_V);

  k_pool  <<<4096, 64, 0, stream>>>(x, pool, xmean);
  k_dcproj<<<64, 256, 0, stream>>>(pool, xmean, dcp1_w, dcp1_g, dcp1_b, dcp2_w, dcp2_b, dc_w, dc_b, wgt, dbias);
  k_y1    <<<2048, 256, 0, stream>>>(x, wgt, dbias, ybf);
  k_qproj <<<3136, 256, 0, stream>>>(x, q_w, q_b, qbf);
  k_srlc  <<<4096, 256, 0, stream>>>(x, sr1_w, sr1_g, sr1_b, sr2_w, sr2_g, sr2_b, lc_w, lc_b, kv3);
  k_kv    <<<896, 256, 0, stream>>>(kv3, kv_w, kv_b, kbf, vbf);
  k_attn  <<<6272, 256, 0, stream>>>(qbf, kbf, vbf, rpe, ybf);
  k_p1    <<<4096, 256, 0, stream>>>(ybf, p1_w, p1_b, p1_g, p1_bb, z1p);
  k_p23m  <<<3136, 256, 0, stream>>>(z1p, ybf, p2_w, p2_b, p2_g, p2_bb, p3_w, p3_b, p3_g, p3_bb, out);
}